// Round 3
// baseline (79.460 us; speedup 1.0000x reference)
//
#include <hip/hip_runtime.h>

#define EPS 1e-8f
#define KCH 512
#define NSP 16
#define NBLOCKS 16          // 8 blocks per batch x 64 channels each
#define NTHR 1024

// ws float-offset layout (counter lives in ws[0..63] cache line)
#define R_OFF    64
#define P0M_OFF  (64 + 1024)
#define P0C_OFF  (64 + 2048)
#define P1M_OFF  (64 + 3072)
#define P1C_OFF  (64 + 4096)

// Single fused kernel, last-block finalize.
// Phase A (all 16 blocks): block (b=blk>>3, grp=blk&7) owns 64 channels.
//   thread t: k_local=t>>4, f=t&15; contiguous coalesced loads of x and the
//   4 W segments; 16-lane shuffle reduce -> per-channel S1,S2 and classifier
//   partials; writes R[k] (max-free Lehmer ratio) + 4 partials to ws.
// Release fence + atomicAdd; 16th arriver acquire-fences and finalizes:
//   rank R within each batch (1 channel-slot per thread), mul = relu(rank
//   difference), combine partials, block-reduce, write logits.
__global__ __launch_bounds__(NTHR)
void ca_fused_kernel(const float* __restrict__ x,
                     const float* __restrict__ W,
                     const float* __restrict__ bias,
                     float* __restrict__ ws,
                     float* __restrict__ out) {
    const int blk = blockIdx.x;
    const int b   = blk >> 3;
    const int grp = blk & 7;
    const int t   = threadIdx.x;
    const int f   = t & 15;

    __shared__ int   last_flag;
    __shared__ float Rsh[2 * KCH];
    __shared__ float red0[16], red1[16];

    // ---- Phase A: moments + classifier partials for 64 channels ----
    {
        const int gidx = grp * 1024 + t;           // within-batch flat index
        const float xv  = x[b * 8192 + gidx];
        const float w0m = W[gidx];
        const float w0c = W[8192  + gidx];
        const float w1m = W[16384 + gidx];
        const float w1c = W[24576 + gidx];

        float s1 = xv, s2 = xv * xv;
        float p0m = xv * w0m, p0c = xv * w0c;
        float p1m = xv * w1m, p1c = xv * w1c;
        #pragma unroll
        for (int off = 8; off > 0; off >>= 1) {
            s1  += __shfl_down(s1,  off, 16);
            s2  += __shfl_down(s2,  off, 16);
            p0m += __shfl_down(p0m, off, 16);
            p0c += __shfl_down(p0c, off, 16);
            p1m += __shfl_down(p1m, off, 16);
            p1c += __shfl_down(p1c, off, 16);
        }
        if (f == 0) {
            const int k = grp * 64 + (t >> 4);
            const int o = b * KCH + k;
            // max-free Lehmer ratio (ordering-equivalent to reference D[k])
            const float nd = s2 + 2.0f * EPS * s1 + 16.0f * EPS * EPS + EPS;
            const float dd = s1 + 17.0f * EPS;
            ws[R_OFF   + o] = nd / dd + EPS;
            ws[P0M_OFF + o] = p0m;
            ws[P0C_OFF + o] = p0c;
            ws[P1M_OFF + o] = p1m;
            ws[P1C_OFF + o] = p1c;
        }
    }
    __syncthreads();
    if (t == 0) {
        __threadfence();  // release: write back this XCD's L2 before signaling
        unsigned old = atomicAdd((unsigned*)ws, 1u);
        last_flag = (old == NBLOCKS - 1) ? 1 : 0;
    }
    __syncthreads();
    if (!last_flag) return;

    // ---- Finalize (last block only) ----
    __threadfence();  // acquire: invalidate local caches before reading ws

    const int b2 = t >> 9;          // 0..1
    const int k2 = t & 511;
    const int o2 = b2 * KCH + k2;

    const float myR = ws[R_OFF + o2];
    Rsh[t] = myR;
    __syncthreads();

    int diff = 0;
    const float* rb = &Rsh[b2 << 9];
    for (int j = 0; j < KCH; j++) {
        const float rj = rb[j];     // uniform per wave -> LDS broadcast
        diff += (myR > rj) ? 1 : 0;
        diff -= (rj > myR) ? 1 : 0;
    }
    float mul = (float)diff;
    if (mul < 0.f) mul = 0.f;

    float acc0 = ws[P0M_OFF + o2] + mul * ws[P0C_OFF + o2];
    float acc1 = ws[P1M_OFF + o2] + mul * ws[P1C_OFF + o2];
    #pragma unroll
    for (int off = 32; off > 0; off >>= 1) {
        acc0 += __shfl_down(acc0, off, 64);
        acc1 += __shfl_down(acc1, off, 64);
    }
    const int wid = t >> 6, lane = t & 63;
    if (lane == 0) { red0[wid] = acc0; red1[wid] = acc1; }
    __syncthreads();
    if (t < 2) {                    // thread 0 -> batch 0, thread 1 -> batch 1
        float s0 = 0.f, s1v = 0.f;
        #pragma unroll
        for (int i = 0; i < 8; i++) {
            s0  += red0[t * 8 + i];
            s1v += red1[t * 8 + i];
        }
        out[t * 2 + 0] = s0  + bias[0];
        out[t * 2 + 1] = s1v + bias[1];
    }
}

extern "C" void kernel_launch(void* const* d_in, const int* in_sizes, int n_in,
                              void* d_out, int out_size, void* d_ws, size_t ws_size,
                              hipStream_t stream) {
    const float* x    = (const float*)d_in[0];  // [2, 512, 4, 4]
    const float* W    = (const float*)d_in[1];  // [2, 16384]
    const float* bias = (const float*)d_in[2];  // [2]
    float* out = (float*)d_out;                 // [2, 2]
    float* ws  = (float*)d_ws;

    hipMemsetAsync(d_ws, 0, 4, stream);         // zero the arrival counter
    ca_fused_kernel<<<NBLOCKS, NTHR, 0, stream>>>(x, W, bias, ws, out);
}

// Round 4
// 68.956 us; speedup vs baseline: 1.1523x; 1.1523x over previous
//
#include <hip/hip_runtime.h>

#define EPS 1e-8f
#define KCH 512
#define NSP 16

// ws float-offset layout (per-channel arrays indexed b*512+k)
#define R_OFF    0
#define P0M_OFF  1024
#define P0C_OFF  2048
#define P1M_OFF  3072
#define P1C_OFF  4096

// ---------------------------------------------------------------------------
// Kernel A: 128 blocks x 128 threads. Block = (batch b, group of 8 channels).
// Per channel k: S1 = sum x, S2 = sum x^2 -> R[k] (max-free Lehmer ratio,
// ordering-identical to reference lehmer_den; validated absmax=0 in R3),
// plus the 4 classifier partials
//   p{c}m = sum_f x*W[c, k*16+f],  p{c}c = sum_f x*W[c, 8192+k*16+f].
// ---------------------------------------------------------------------------
__global__ __launch_bounds__(128)
void partials_kernel(const float* __restrict__ x,
                     const float* __restrict__ W,
                     float* __restrict__ ws) {
    const int blk = blockIdx.x;
    const int b   = blk >> 6;        // 64 blocks per batch
    const int grp = blk & 63;
    const int t   = threadIdx.x;
    const int f   = t & 15;
    const int gidx = grp * 128 + t;  // within-batch flat index (k*16+f)

    const float xv  = x[b * 8192 + gidx];
    const float w0m = W[gidx];
    const float w0c = W[8192  + gidx];
    const float w1m = W[16384 + gidx];
    const float w1c = W[24576 + gidx];

    float s1 = xv, s2 = xv * xv;
    float p0m = xv * w0m, p0c = xv * w0c;
    float p1m = xv * w1m, p1c = xv * w1c;
    #pragma unroll
    for (int off = 8; off > 0; off >>= 1) {
        s1  += __shfl_down(s1,  off, 16);
        s2  += __shfl_down(s2,  off, 16);
        p0m += __shfl_down(p0m, off, 16);
        p0c += __shfl_down(p0c, off, 16);
        p1m += __shfl_down(p1m, off, 16);
        p1c += __shfl_down(p1c, off, 16);
    }
    if (f == 0) {
        const int k = grp * 8 + (t >> 4);
        const int o = b * KCH + k;
        const float nd = s2 + 2.0f * EPS * s1 + 16.0f * EPS * EPS + EPS;
        const float dd = s1 + 17.0f * EPS;
        ws[R_OFF   + o] = nd / dd + EPS;
        ws[P0M_OFF + o] = p0m;
        ws[P0C_OFF + o] = p0c;
        ws[P1M_OFF + o] = p1m;
        ws[P1C_OFF + o] = p1c;
    }
}

// ---------------------------------------------------------------------------
// Kernel B: 2 blocks x 512 threads (block = batch). Rank R -> mul factors
// (exact integers, two strict compares like the reference STE pair),
// combine classifier partials, block-reduce, write logits.
// ---------------------------------------------------------------------------
__global__ __launch_bounds__(512)
void finalize_kernel(const float* __restrict__ ws,
                     const float* __restrict__ bias,
                     float* __restrict__ out) {
    const int b = blockIdx.x;
    const int t = threadIdx.x;
    const int wid = t >> 6, lane = t & 63;

    __shared__ float Rsh[KCH];
    __shared__ float red0[8], red1[8];

    const int o = b * KCH + t;
    const float myR = ws[R_OFF + o];
    Rsh[t] = myR;

    // issue partial loads early; latency hides under the rank loop
    const float p0m = ws[P0M_OFF + o];
    const float p0c = ws[P0C_OFF + o];
    const float p1m = ws[P1M_OFF + o];
    const float p1c = ws[P1C_OFF + o];
    __syncthreads();

    int diff = 0;
    #pragma unroll 8
    for (int j = 0; j < KCH; j++) {
        const float rj = Rsh[j];    // uniform per wave -> LDS broadcast
        diff += (myR > rj) ? 1 : 0;
        diff -= (rj > myR) ? 1 : 0;
    }
    float mul = (float)diff;
    if (mul < 0.f) mul = 0.f;       // relu

    float acc0 = p0m + mul * p0c;
    float acc1 = p1m + mul * p1c;
    #pragma unroll
    for (int off = 32; off > 0; off >>= 1) {
        acc0 += __shfl_down(acc0, off, 64);
        acc1 += __shfl_down(acc1, off, 64);
    }
    if (lane == 0) { red0[wid] = acc0; red1[wid] = acc1; }
    __syncthreads();
    if (t == 0) {
        float s0 = 0.f, s1 = 0.f;
        #pragma unroll
        for (int i = 0; i < 8; i++) { s0 += red0[i]; s1 += red1[i]; }
        out[b * 2 + 0] = s0 + bias[0];
        out[b * 2 + 1] = s1 + bias[1];
    }
}

extern "C" void kernel_launch(void* const* d_in, const int* in_sizes, int n_in,
                              void* d_out, int out_size, void* d_ws, size_t ws_size,
                              hipStream_t stream) {
    const float* x    = (const float*)d_in[0];  // [2, 512, 4, 4]
    const float* W    = (const float*)d_in[1];  // [2, 16384]
    const float* bias = (const float*)d_in[2];  // [2]
    float* out = (float*)d_out;                 // [2, 2]
    float* ws  = (float*)d_ws;

    partials_kernel<<<128, 128, 0, stream>>>(x, W, ws);
    finalize_kernel<<<2, 512, 0, stream>>>(ws, bias, out);
}